// Round 10
// baseline (38.077 us; speedup 1.0000x reference)
//
#include <hip/hip_runtime.h>

#define Bn 4
#define Mn 100
#define Dn 128
#define NB (2 * Bn * 256)   // gather grid: 2 blocks per row
#define NZ 804              // floats zeroed by flag: gsum[400] gcnt[400] ticket pad

// ---------------- K1: flags -> deterministic per-row cell lists (verbatim R9, verified)
__global__ __launch_bounds__(256) void flag_kernel(
    const float* __restrict__ boxes,
    unsigned int* __restrict__ rowcnt,
    unsigned int* __restrict__ cells,
    float* __restrict__ gz)            // gsum|gcnt|ticket region: NZ floats
{
    __shared__ float abox[Mn * 18];
    __shared__ int   am[Mn];
    __shared__ int   wcnt[4], wbase[4];
    __shared__ int   nactS, nflag;
    __shared__ int   clist[256];

    const int b  = blockIdx.x >> 8;
    const int y  = blockIdx.x & 255;
    const int tx = threadIdx.x;

    // zero the accumulator+ticket region (visible to gather via kernel boundary)
    if (blockIdx.x < NZ && tx == 0) gz[blockIdx.x] = 0.0f;
    if (tx == 0) nflag = 0;

    const float DIMS0 = 51.2f + 51.2f;
    float gy = __fadd_rn(__fmul_rn((y + 0.5f) * (1.0f / 256.0f), DIMS0), -51.2f);

    // geometry in registers (exact arithmetic of the verified rounds)
    float px[4], py[4], ex[4], ey[4];
    bool act = false;
    if (tx < Mn) {
        const float* bx = boxes + (size_t)(b * Mn + tx) * 7;
        float cx = bx[0], cy = bx[1];
        float l = bx[3], w = bx[4], yaw = bx[6];
        const float cellw = DIMS0 / 256.0f;
        float rl = fminf(fmaxf(cellw / l, 1.0f), 6.0f);
        float rw = fminf(fmaxf(cellw / w, 1.0f), 6.0f);
        float el = __fmul_rn(l, rl);
        float ew = __fmul_rn(w, rw);
        float c = cosf(yaw), s = sinf(yaw);
        const float nx[4] = {-0.5f, -0.5f, 0.5f, 0.5f};
        const float ny[4] = {-0.5f, 0.5f, 0.5f, -0.5f};
        #pragma unroll
        for (int k = 0; k < 4; k++) {
            float ox = __fmul_rn(el, nx[k]);
            float oy = __fmul_rn(ew, ny[k]);
            float rx = __fadd_rn(__fmul_rn(ox, c), __fmul_rn(oy, s));
            float ry = __fadd_rn(__fmul_rn(-ox, s), __fmul_rn(oy, c));
            px[k] = __fadd_rn(rx, cx);
            py[k] = __fadd_rn(ry, cy);
        }
        #pragma unroll
        for (int k = 0; k < 4; k++) {
            ex[k] = __fsub_rn(px[(k + 1) & 3], px[k]);
            ey[k] = __fsub_rn(py[(k + 1) & 3], py[k]);
        }
        float r = 0.5f * sqrtf(el * el + ew * ew) + 0.01f;
        act = fabsf(gy - cy) <= r;       // conservative y-band
    }

    // order-preserving compaction of y-active boxes (m order preserved)
    unsigned long long mb = __ballot(act);
    int wid = tx >> 6;
    if ((tx & 63) == 0) wcnt[wid] = __popcll(mb);
    __syncthreads();
    if (tx == 0) {
        wbase[0] = 0;
        wbase[1] = wcnt[0];
        wbase[2] = wcnt[0] + wcnt[1];
        wbase[3] = wbase[2] + wcnt[2];
        nactS    = wbase[3] + wcnt[3];
    }
    __syncthreads();
    const int nact = nactS;
    if (nact == 0) {                      // no box touches this row
        if (tx == 0) rowcnt[blockIdx.x] = 0;
        return;
    }
    if (act) {
        int slot = wbase[wid] + __popcll(mb & ((1ull << (tx & 63)) - 1ull));
        float* o = abox + slot * 18;
        #pragma unroll
        for (int k = 0; k < 4; k++) {
            o[k * 2] = px[k];  o[k * 2 + 1] = py[k];
            o[8 + k * 2] = ex[k]; o[8 + k * 2 + 1] = ey[k];
        }
        am[slot] = tx;
    }
    __syncthreads();

    // per-cell parity scan over the ~5 y-active boxes (broadcast LDS reads)
    float gx = __fadd_rn(__fmul_rn((tx + 0.5f) * (1.0f / 256.0f), DIMS0), -51.2f);
    int flag = -1;
    for (int j = 0; j < nact; j++) {
        const float* o = &abox[j * 18];
        bool ge = true, le = true;
        #pragma unroll
        for (int k = 0; k < 4; k++) {
            float dx = __fsub_rn(gx, o[k * 2]);
            float dy = __fsub_rn(gy, o[k * 2 + 1]);
            float cr = __fsub_rn(__fmul_rn(o[8 + k * 2], dy),
                                 __fmul_rn(o[8 + k * 2 + 1], dx));
            ge = ge && (cr >= 0.0f);
            le = le && (cr <= 0.0f);
        }
        if (ge || le) flag = (flag == -1) ? am[j] : -1;
    }

    if (flag >= 0) {
        int idx = atomicAdd(&nflag, 1);
        clist[idx] = (flag << 8) | tx;    // m (7b) | x (8b)
    }
    __syncthreads();
    if (tx == 0) rowcnt[blockIdx.x] = nflag;
    for (int i = tx; i < nflag; i += 256)
        cells[(blockIdx.x << 8) + i] = clist[i];
}

// ---------------- K2: sparse gather + relaxed-ticket last-block finalize (no fences)
__global__ __launch_bounds__(256) void gather_kernel(
    const float* __restrict__ atten,
    const unsigned int* __restrict__ rowcnt,
    const unsigned int* __restrict__ cells,
    float* __restrict__ gsum, float* __restrict__ gcnt,
    unsigned int* __restrict__ ticket, float* __restrict__ out)
{
    __shared__ float ssum[Mn], scnt[Mn];
    __shared__ int lastS;
    const int tx   = threadIdx.x;
    const int row  = blockIdx.x >> 1;        // 0..1023 = b*256+y
    const int half = blockIdx.x & 1;
    const int b    = row >> 8;
    const unsigned int n = rowcnt[row];      // block-uniform

    if (tx < Mn) { ssum[tx] = 0.0f; scnt[tx] = 0.0f; }

    if (n != 0) {                            // block-uniform branch
        __syncthreads();
        const int g    = (half << 4) + (tx >> 4);   // 0..31 groups across the row
        const int lane = tx & 15;
        const unsigned int base = (unsigned int)row << 8;
        const size_t rowbase = (size_t)base;

        for (unsigned int j = g; j < n; j += 64) {
            unsigned int e0 = cells[base + j];
            unsigned int j1 = j + 32;
            bool h1 = j1 < n;
            unsigned int e1 = h1 ? cells[base + j1] : e0;
            const float4* p0 = reinterpret_cast<const float4*>(
                atten + (rowbase + (e0 & 255)) * Dn);
            const float4* p1 = reinterpret_cast<const float4*>(
                atten + (rowbase + (e1 & 255)) * Dn);
            float4 a0 = p0[lane];
            float4 b0 = p0[lane + 16];
            float4 a1 = p1[lane];
            float4 b1 = p1[lane + 16];          // 4 independent loads in flight

            float s0 = (a0.x + a0.y + a0.z + a0.w) + (b0.x + b0.y + b0.z + b0.w);
            float q0 = (a0.x * a0.x + a0.y * a0.y + a0.z * a0.z + a0.w * a0.w)
                     + (b0.x * b0.x + b0.y * b0.y + b0.z * b0.z + b0.w * b0.w);
            float s1 = (a1.x + a1.y + a1.z + a1.w) + (b1.x + b1.y + b1.z + b1.w);
            float q1 = (a1.x * a1.x + a1.y * a1.y + a1.z * a1.z + a1.w * a1.w)
                     + (b1.x * b1.x + b1.y * b1.y + b1.z * b1.z + b1.w * b1.w);
            #pragma unroll
            for (int d = 8; d; d >>= 1) {
                s0 += __shfl_xor(s0, d);
                q0 += __shfl_xor(q0, d);
                s1 += __shfl_xor(s1, d);
                q1 += __shfl_xor(q1, d);
            }
            if (lane == 0) {
                float v0 = (q0 - s0 * s0 * (1.0f / 128.0f)) * (1.0f / 127.0f);
                atomicAdd(&ssum[e0 >> 8], v0);
                atomicAdd(&scnt[e0 >> 8], 1.0f);
                if (h1) {
                    float v1 = (q1 - s1 * s1 * (1.0f / 128.0f)) * (1.0f / 127.0f);
                    atomicAdd(&ssum[e1 >> 8], v1);
                    atomicAdd(&scnt[e1 >> 8], 1.0f);
                }
            }
        }
        __syncthreads();
        if (tx < Mn && scnt[tx] > 0.0f) {
            atomicAdd(&gsum[b * Mn + tx], ssum[tx]);
            atomicAdd(&gcnt[b * Mn + tx], scnt[tx]);
        }
    }

    // barrier drains each wave's outstanding global atomics (compiler emits
    // s_waitcnt vmcnt(0) before s_barrier) -> adds complete at coherence point
    // before the relaxed ticket increment. No release fence needed.
    __syncthreads();
    if (tx == 0) {
        unsigned int t = __hip_atomic_fetch_add(ticket, 1u, __ATOMIC_RELAXED,
                                                __HIP_MEMORY_SCOPE_AGENT);
        lastS = (t == (unsigned int)(NB - 1)) ? 1 : 0;
    }
    __syncthreads();
    if (!lastS) return;

    // last block: read accumulators via agent-scope atomic loads (bypass stale L2)
    float loss = 0.0f, num = 0.0f;
    for (int i = tx; i < Bn * Mn; i += 256) {
        float c = __hip_atomic_load(&gcnt[i], __ATOMIC_RELAXED, __HIP_MEMORY_SCOPE_AGENT);
        if (c > 0.0f) {
            float sL = __hip_atomic_load(&gsum[i], __ATOMIC_RELAXED, __HIP_MEMORY_SCOPE_AGENT);
            loss -= sL / fmaxf(c, 1.0f);
            num  += 1.0f;
        }
    }
    #pragma unroll
    for (int d = 32; d; d >>= 1) {
        loss += __shfl_xor(loss, d);
        num  += __shfl_xor(num, d);
    }
    if ((tx & 63) == 0) { ssum[tx >> 6] = loss; scnt[tx >> 6] = num; }
    __syncthreads();
    if (tx == 0) {
        float L = ssum[0] + ssum[1] + ssum[2] + ssum[3];
        float N = scnt[0] + scnt[1] + scnt[2] + scnt[3];
        out[0] = L / fmaxf(N, 1.0f);
    }
}

extern "C" void kernel_launch(void* const* d_in, const int* in_sizes, int n_in,
                              void* d_out, int out_size, void* d_ws, size_t ws_size,
                              hipStream_t stream) {
    const float* atten = (const float*)d_in[0];
    const float* boxes = (const float*)d_in[1];
    float* out = (float*)d_out;

    // ws layout: gsum[400] | gcnt[400] | ticket @+3200 | rowcnt @+3328 | cells @+8192
    float* gsum = (float*)d_ws;
    float* gcnt = gsum + Bn * Mn;
    unsigned int* ticket = (unsigned int*)((char*)d_ws + 3200);
    unsigned int* rowcnt = (unsigned int*)((char*)d_ws + 3328);
    unsigned int* cells  = (unsigned int*)((char*)d_ws + 8192);

    flag_kernel<<<Bn * 256, 256, 0, stream>>>(boxes, rowcnt, cells, gsum);
    gather_kernel<<<NB, 256, 0, stream>>>(atten, rowcnt, cells, gsum, gcnt, ticket, out);
}

// Round 11
// 26.986 us; speedup vs baseline: 1.4110x; 1.4110x over previous
//
#include <hip/hip_runtime.h>

#define Bn 4
#define Mn 100
#define Dn 128

// ---------------- K1: one block per (scene, box): flag-partition + gather.
// No global atomics, no init required: every block writes its bout slot.
__global__ __launch_bounds__(256) void box_kernel(
    const float* __restrict__ atten,
    const float* __restrict__ boxes,
    float2* __restrict__ bout)          // Bn*Mn slots: (sum, count)
{
    __shared__ float sb[Mn * 18];
    __shared__ int   clist[512];
    __shared__ int   ncell;
    __shared__ float bsum;

    const int bm = blockIdx.x;          // 0..399
    const int b  = bm / Mn;
    const int m  = bm - b * Mn;
    const int tx = threadIdx.x;

    if (tx == 0) { ncell = 0; bsum = 0.0f; }

    // geometry staging for ALL boxes of scene b (verbatim verified arithmetic)
    const float DIMS0 = 51.2f + 51.2f;
    if (tx < Mn) {
        const float* bx = boxes + (size_t)(b * Mn + tx) * 7;
        float cx = bx[0], cy = bx[1];
        float l = bx[3], w = bx[4], yaw = bx[6];
        const float cellw = DIMS0 / 256.0f;
        float rl = fminf(fmaxf(cellw / l, 1.0f), 6.0f);
        float rw = fminf(fmaxf(cellw / w, 1.0f), 6.0f);
        float el = __fmul_rn(l, rl);
        float ew = __fmul_rn(w, rw);
        float c = cosf(yaw), s = sinf(yaw);
        const float nx[4] = {-0.5f, -0.5f, 0.5f, 0.5f};
        const float ny[4] = {-0.5f, 0.5f, 0.5f, -0.5f};
        float px[4], py[4];
        #pragma unroll
        for (int k = 0; k < 4; k++) {
            float ox = __fmul_rn(el, nx[k]);
            float oy = __fmul_rn(ew, ny[k]);
            float rx = __fadd_rn(__fmul_rn(ox, c), __fmul_rn(oy, s));
            float ry = __fadd_rn(__fmul_rn(-ox, s), __fmul_rn(oy, c));
            px[k] = __fadd_rn(rx, cx);
            py[k] = __fadd_rn(ry, cy);
        }
        float* o = sb + tx * 18;
        #pragma unroll
        for (int k = 0; k < 4; k++) { o[k * 2] = px[k]; o[k * 2 + 1] = py[k]; }
        #pragma unroll
        for (int k = 0; k < 4; k++) {
            o[8 + k * 2]     = __fsub_rn(px[(k + 1) & 3], px[k]);
            o[8 + k * 2 + 1] = __fsub_rn(py[(k + 1) & 3], py[k]);
        }
        o[16] = cy;
        o[17] = 0.5f * sqrtf(el * el + ew * ew) + 0.01f;  // conservative radius
    }
    __syncthreads();

    // candidate rectangle for box m (covers all cells possibly inside box m)
    const float cxm = boxes[(size_t)(b * Mn + m) * 7];
    const float cym = sb[m * 18 + 16];
    const float rm  = sb[m * 18 + 17];
    int ix_lo = max(0,   (int)floorf((cxm - rm + 51.2f) * 2.5f - 0.5f) - 1);
    int ix_hi = min(255, (int)ceilf ((cxm + rm + 51.2f) * 2.5f - 0.5f) + 1);
    int iy_lo = max(0,   (int)floorf((cym - rm + 51.2f) * 2.5f - 0.5f) - 1);
    int iy_hi = min(255, (int)ceilf ((cym + rm + 51.2f) * 2.5f - 0.5f) + 1);
    const int wx  = ix_hi - ix_lo + 1;
    const int wy  = iy_hi - iy_lo + 1;
    const int tot = (wx > 0 && wy > 0) ? wx * wy : 0;

    // full ordered parity scan per candidate cell (bit-identical flag semantics)
    for (int cidx = tx; cidx < tot; cidx += 256) {
        int ry = cidx / wx;
        int ix = ix_lo + (cidx - ry * wx);
        int iy = iy_lo + ry;
        float gx = __fadd_rn(__fmul_rn((ix + 0.5f) * (1.0f / 256.0f), DIMS0), -51.2f);
        float gy = __fadd_rn(__fmul_rn((iy + 0.5f) * (1.0f / 256.0f), DIMS0), -51.2f);
        int flag = -1;
        for (int j = 0; j < Mn; j++) {
            const float* o = &sb[j * 18];
            if (fabsf(gy - o[16]) > o[17]) continue;   // conservative y-band
            bool ge = true, le = true;
            #pragma unroll
            for (int k = 0; k < 4; k++) {
                float dx = __fsub_rn(gx, o[k * 2]);
                float dy = __fsub_rn(gy, o[k * 2 + 1]);
                float cr = __fsub_rn(__fmul_rn(o[8 + k * 2], dy),
                                     __fmul_rn(o[8 + k * 2 + 1], dx));
                ge = ge && (cr >= 0.0f);
                le = le && (cr <= 0.0f);
            }
            if (ge || le) flag = (flag == -1) ? j : -1;
        }
        if (flag == m) {
            int id = atomicAdd(&ncell, 1);
            if (id < 512) clist[id] = (iy << 8) | ix;
        }
    }
    __syncthreads();
    const int n = min(ncell, 512);

    // gather variance for this box's cells: 16-lane groups, float8/lane, 2-way unroll
    if (n > 0) {
        const int g = tx >> 4, lane = tx & 15;       // 16 groups of 16 lanes
        const size_t scb = (size_t)b << 16;          // b*65536 flat row base
        for (int j = g; j < n; j += 32) {
            int e0 = clist[j];
            int j1 = j + 16;
            bool h1 = j1 < n;
            int e1 = h1 ? clist[j1] : e0;
            const float4* p0 = reinterpret_cast<const float4*>(
                atten + (scb + ((e0 >> 8) << 8) + (e0 & 255)) * Dn);
            const float4* p1 = reinterpret_cast<const float4*>(
                atten + (scb + ((e1 >> 8) << 8) + (e1 & 255)) * Dn);
            float4 a0 = p0[lane];
            float4 b0 = p0[lane + 16];
            float4 a1 = p1[lane];
            float4 b1 = p1[lane + 16];               // 4 independent loads in flight

            float s0 = (a0.x + a0.y + a0.z + a0.w) + (b0.x + b0.y + b0.z + b0.w);
            float q0 = (a0.x * a0.x + a0.y * a0.y + a0.z * a0.z + a0.w * a0.w)
                     + (b0.x * b0.x + b0.y * b0.y + b0.z * b0.z + b0.w * b0.w);
            float s1 = (a1.x + a1.y + a1.z + a1.w) + (b1.x + b1.y + b1.z + b1.w);
            float q1 = (a1.x * a1.x + a1.y * a1.y + a1.z * a1.z + a1.w * a1.w)
                     + (b1.x * b1.x + b1.y * b1.y + b1.z * b1.z + b1.w * b1.w);
            #pragma unroll
            for (int d = 8; d; d >>= 1) {
                s0 += __shfl_xor(s0, d);
                q0 += __shfl_xor(q0, d);
                s1 += __shfl_xor(s1, d);
                q1 += __shfl_xor(q1, d);
            }
            if (lane == 0) {
                float v0 = (q0 - s0 * s0 * (1.0f / 128.0f)) * (1.0f / 127.0f);
                float vv = v0;
                if (h1)
                    vv += (q1 - s1 * s1 * (1.0f / 128.0f)) * (1.0f / 127.0f);
                atomicAdd(&bsum, vv);
            }
        }
    }
    __syncthreads();
    if (tx == 0) bout[bm] = make_float2(bsum, (float)n);   // unconditional
}

// ---------------- K2: finalize scalar loss (1 block)
__global__ __launch_bounds__(512) void final_kernel(const float2* __restrict__ bout,
                                                    float* __restrict__ out) {
    __shared__ float sl[8], sn[8];
    int t = threadIdx.x;
    float loss = 0.0f, num = 0.0f;
    if (t < Bn * Mn) {
        float2 v = bout[t];
        if (v.y > 0.0f) {
            loss = -(v.x / fmaxf(v.y, 1.0f));
            num  = 1.0f;
        }
    }
    #pragma unroll
    for (int d = 32; d; d >>= 1) {
        loss += __shfl_xor(loss, d);
        num  += __shfl_xor(num, d);
    }
    if ((t & 63) == 0) { sl[t >> 6] = loss; sn[t >> 6] = num; }
    __syncthreads();
    if (t == 0) {
        float L = 0.0f, N = 0.0f;
        #pragma unroll
        for (int i = 0; i < 8; i++) { L += sl[i]; N += sn[i]; }
        out[0] = L / fmaxf(N, 1.0f);
    }
}

extern "C" void kernel_launch(void* const* d_in, const int* in_sizes, int n_in,
                              void* d_out, int out_size, void* d_ws, size_t ws_size,
                              hipStream_t stream) {
    const float* atten = (const float*)d_in[0];
    const float* boxes = (const float*)d_in[1];
    float* out = (float*)d_out;

    float2* bout = (float2*)d_ws;       // 400 float2 = 3.2 KB, fully overwritten

    box_kernel<<<Bn * Mn, 256, 0, stream>>>(atten, boxes, bout);
    final_kernel<<<1, 512, 0, stream>>>(bout, out);
}

// Round 12
// 19.269 us; speedup vs baseline: 1.9761x; 1.4005x over previous
//
#include <hip/hip_runtime.h>

#define Bn 4
#define Mn 100
#define Dn 128

// ---------------- K1: flags -> deterministic per-row cell lists (verbatim R5/R9, verified)
__global__ __launch_bounds__(256) void flag_kernel(
    const float* __restrict__ boxes,
    unsigned int* __restrict__ rowcnt,
    unsigned int* __restrict__ cells,
    float* __restrict__ gz)            // gsum|gcnt region: 2*Bn*Mn floats
{
    __shared__ float abox[Mn * 18];
    __shared__ int   am[Mn];
    __shared__ int   wcnt[4], wbase[4];
    __shared__ int   nactS, nflag;
    __shared__ int   clist[256];

    const int b  = blockIdx.x >> 8;
    const int y  = blockIdx.x & 255;
    const int tx = threadIdx.x;

    // zero the accumulator region (visible to gather via kernel boundary)
    if (blockIdx.x < 2 * Bn * Mn && tx == 0) gz[blockIdx.x] = 0.0f;
    if (tx == 0) nflag = 0;

    const float DIMS0 = 51.2f + 51.2f;
    float gy = __fadd_rn(__fmul_rn((y + 0.5f) * (1.0f / 256.0f), DIMS0), -51.2f);

    // geometry in registers (exact arithmetic of the verified rounds)
    float px[4], py[4], ex[4], ey[4];
    bool act = false;
    if (tx < Mn) {
        const float* bx = boxes + (size_t)(b * Mn + tx) * 7;
        float cx = bx[0], cy = bx[1];
        float l = bx[3], w = bx[4], yaw = bx[6];
        const float cellw = DIMS0 / 256.0f;
        float rl = fminf(fmaxf(cellw / l, 1.0f), 6.0f);
        float rw = fminf(fmaxf(cellw / w, 1.0f), 6.0f);
        float el = __fmul_rn(l, rl);
        float ew = __fmul_rn(w, rw);
        float c = cosf(yaw), s = sinf(yaw);
        const float nx[4] = {-0.5f, -0.5f, 0.5f, 0.5f};
        const float ny[4] = {-0.5f, 0.5f, 0.5f, -0.5f};
        #pragma unroll
        for (int k = 0; k < 4; k++) {
            float ox = __fmul_rn(el, nx[k]);
            float oy = __fmul_rn(ew, ny[k]);
            float rx = __fadd_rn(__fmul_rn(ox, c), __fmul_rn(oy, s));
            float ry = __fadd_rn(__fmul_rn(-ox, s), __fmul_rn(oy, c));
            px[k] = __fadd_rn(rx, cx);
            py[k] = __fadd_rn(ry, cy);
        }
        #pragma unroll
        for (int k = 0; k < 4; k++) {
            ex[k] = __fsub_rn(px[(k + 1) & 3], px[k]);
            ey[k] = __fsub_rn(py[(k + 1) & 3], py[k]);
        }
        float r = 0.5f * sqrtf(el * el + ew * ew) + 0.01f;
        act = fabsf(gy - cy) <= r;       // conservative y-band
    }

    // order-preserving compaction of y-active boxes (m order preserved)
    unsigned long long mb = __ballot(act);
    int wid = tx >> 6;
    if ((tx & 63) == 0) wcnt[wid] = __popcll(mb);
    __syncthreads();
    if (tx == 0) {
        wbase[0] = 0;
        wbase[1] = wcnt[0];
        wbase[2] = wcnt[0] + wcnt[1];
        wbase[3] = wbase[2] + wcnt[2];
        nactS    = wbase[3] + wcnt[3];
    }
    __syncthreads();
    const int nact = nactS;
    if (nact == 0) {                      // no box touches this row
        if (tx == 0) rowcnt[blockIdx.x] = 0;
        return;
    }
    if (act) {
        int slot = wbase[wid] + __popcll(mb & ((1ull << (tx & 63)) - 1ull));
        float* o = abox + slot * 18;
        #pragma unroll
        for (int k = 0; k < 4; k++) {
            o[k * 2] = px[k];  o[k * 2 + 1] = py[k];
            o[8 + k * 2] = ex[k]; o[8 + k * 2 + 1] = ey[k];
        }
        am[slot] = tx;
    }
    __syncthreads();

    // per-cell parity scan over the ~5 y-active boxes (broadcast LDS reads)
    float gx = __fadd_rn(__fmul_rn((tx + 0.5f) * (1.0f / 256.0f), DIMS0), -51.2f);
    int flag = -1;
    for (int j = 0; j < nact; j++) {
        const float* o = &abox[j * 18];
        bool ge = true, le = true;
        #pragma unroll
        for (int k = 0; k < 4; k++) {
            float dx = __fsub_rn(gx, o[k * 2]);
            float dy = __fsub_rn(gy, o[k * 2 + 1]);
            float cr = __fsub_rn(__fmul_rn(o[8 + k * 2], dy),
                                 __fmul_rn(o[8 + k * 2 + 1], dx));
            ge = ge && (cr >= 0.0f);
            le = le && (cr <= 0.0f);
        }
        if (ge || le) flag = (flag == -1) ? am[j] : -1;
    }

    if (flag >= 0) {
        int idx = atomicAdd(&nflag, 1);
        clist[idx] = (flag << 8) | tx;    // m (7b) | x (8b)
    }
    __syncthreads();
    if (tx == 0) rowcnt[blockIdx.x] = nflag;
    for (int i = tx; i < nflag; i += 256)
        cells[(blockIdx.x << 8) + i] = clist[i];
}

// ---------------- K2: sparse variance gather — 16-lane groups (float8/lane),
//                     2 blocks/row (32 groups) + 2-way row unroll
__global__ __launch_bounds__(256) void gather_kernel(
    const float* __restrict__ atten,
    const unsigned int* __restrict__ rowcnt,
    const unsigned int* __restrict__ cells,
    float* __restrict__ gsum, float* __restrict__ gcnt)
{
    __shared__ float ssum[Mn], scnt[Mn];
    const int tx   = threadIdx.x;
    const int row  = blockIdx.x >> 1;        // 0..1023 = b*256+y
    const int half = blockIdx.x & 1;
    const int b    = row >> 8;
    const unsigned int n = rowcnt[row];

    if (tx < Mn) { ssum[tx] = 0.0f; scnt[tx] = 0.0f; }
    if (n == 0) return;                      // block-uniform
    __syncthreads();

    const int g    = (half << 4) + (tx >> 4);   // 0..31 groups across the row
    const int lane = tx & 15;
    const unsigned int base = (unsigned int)row << 8;
    const size_t rowbase = (size_t)base;

    for (unsigned int j = g; j < n; j += 64) {
        unsigned int e0 = cells[base + j];
        unsigned int j1 = j + 32;
        bool h1 = j1 < n;
        unsigned int e1 = h1 ? cells[base + j1] : e0;
        const float4* p0 = reinterpret_cast<const float4*>(
            atten + (rowbase + (e0 & 255)) * Dn);
        const float4* p1 = reinterpret_cast<const float4*>(
            atten + (rowbase + (e1 & 255)) * Dn);
        float4 a0 = p0[lane];
        float4 b0 = p0[lane + 16];
        float4 a1 = p1[lane];
        float4 b1 = p1[lane + 16];          // 4 independent loads in flight

        float s0 = (a0.x + a0.y + a0.z + a0.w) + (b0.x + b0.y + b0.z + b0.w);
        float q0 = (a0.x * a0.x + a0.y * a0.y + a0.z * a0.z + a0.w * a0.w)
                 + (b0.x * b0.x + b0.y * b0.y + b0.z * b0.z + b0.w * b0.w);
        float s1 = (a1.x + a1.y + a1.z + a1.w) + (b1.x + b1.y + b1.z + b1.w);
        float q1 = (a1.x * a1.x + a1.y * a1.y + a1.z * a1.z + a1.w * a1.w)
                 + (b1.x * b1.x + b1.y * b1.y + b1.z * b1.z + b1.w * b1.w);
        #pragma unroll
        for (int d = 8; d; d >>= 1) {
            s0 += __shfl_xor(s0, d);
            q0 += __shfl_xor(q0, d);
            s1 += __shfl_xor(s1, d);
            q1 += __shfl_xor(q1, d);
        }
        if (lane == 0) {
            float v0 = (q0 - s0 * s0 * (1.0f / 128.0f)) * (1.0f / 127.0f);
            atomicAdd(&ssum[e0 >> 8], v0);
            atomicAdd(&scnt[e0 >> 8], 1.0f);
            if (h1) {
                float v1 = (q1 - s1 * s1 * (1.0f / 128.0f)) * (1.0f / 127.0f);
                atomicAdd(&ssum[e1 >> 8], v1);
                atomicAdd(&scnt[e1 >> 8], 1.0f);
            }
        }
    }
    __syncthreads();
    if (tx < Mn && scnt[tx] > 0.0f) {
        atomicAdd(&gsum[b * Mn + tx], ssum[tx]);
        atomicAdd(&gcnt[b * Mn + tx], scnt[tx]);
    }
}

// ---------------- K3: finalize scalar loss (1 block; verbatim R5/R9, verified)
__global__ __launch_bounds__(512) void final_kernel(const float* __restrict__ gsum,
                                                    const float* __restrict__ gcnt,
                                                    float* __restrict__ out) {
    __shared__ float sl[8], sn[8];
    int t = threadIdx.x;
    float loss = 0.0f, num = 0.0f;
    if (t < Bn * Mn) {
        float c = gcnt[t];
        if (c > 0.0f) {
            loss = -(gsum[t] / fmaxf(c, 1.0f));
            num = 1.0f;
        }
    }
    #pragma unroll
    for (int m = 32; m; m >>= 1) {
        loss += __shfl_xor(loss, m);
        num  += __shfl_xor(num, m);
    }
    if ((t & 63) == 0) { sl[t >> 6] = loss; sn[t >> 6] = num; }
    __syncthreads();
    if (t == 0) {
        float L = 0.0f, N = 0.0f;
        #pragma unroll
        for (int i = 0; i < 8; i++) { L += sl[i]; N += sn[i]; }
        out[0] = L / fmaxf(N, 1.0f);
    }
}

extern "C" void kernel_launch(void* const* d_in, const int* in_sizes, int n_in,
                              void* d_out, int out_size, void* d_ws, size_t ws_size,
                              hipStream_t stream) {
    const float* atten = (const float*)d_in[0];
    const float* boxes = (const float*)d_in[1];
    float* out = (float*)d_out;

    // ws layout: gsum[400] | gcnt[400] | rowcnt[1024] @+3200 | cells @+8192 (1 MB)
    float* gsum = (float*)d_ws;
    float* gcnt = gsum + Bn * Mn;
    unsigned int* rowcnt = (unsigned int*)((char*)d_ws + 3200);
    unsigned int* cells  = (unsigned int*)((char*)d_ws + 8192);

    flag_kernel<<<Bn * 256, 256, 0, stream>>>(boxes, rowcnt, cells, gsum);
    gather_kernel<<<2 * Bn * 256, 256, 0, stream>>>(atten, rowcnt, cells, gsum, gcnt);
    final_kernel<<<1, 512, 0, stream>>>(gsum, gcnt, out);
}